// Round 3
// baseline (4130.687 us; speedup 1.0000x reference)
//
#include <hip/hip_runtime.h>
#include <stdint.h>

#define T_    512
#define H_    256
#define OUTD  128
#define DEPTH 8          // exchange ring depth (slots); slack removes back-pressure RT

typedef unsigned long long u64;
typedef __attribute__((ext_vector_type(8))) short s8v;
typedef __attribute__((ext_vector_type(4))) float f4v;

__device__ __forceinline__ f4v mfma16x16x32(s8v a, s8v b, f4v c) {
  return __builtin_amdgcn_mfma_f32_16x16x32_bf16(a, b, c, 0, 0, 0);
}

// fp32 -> bf16 hi (truncate) + bf16 lo (RN of remainder)
__device__ __forceinline__ void split_bf16(float f, short &hi, short &lo) {
  unsigned u  = __float_as_uint(f);
  unsigned uh = u & 0xffff0000u;
  hi = (short)(uh >> 16);
  float r = f - __uint_as_float(uh);
  unsigned ur = __float_as_uint(r);
  lo = (short)((ur + 0x7fffu + ((ur >> 16) & 1u)) >> 16);
}

__device__ __forceinline__ unsigned pack_hilo(float f) {
  short hi, lo; split_bf16(f, hi, lo);
  return ((unsigned)(unsigned short)hi << 16) | (unsigned)(unsigned short)lo;
}

__device__ __forceinline__ float sig_(float x) { return 1.f / (1.f + __expf(-x)); }
__device__ __forceinline__ float th_(float x)  { float e = __expf(2.f * x); return 1.f - 2.f / (e + 1.f); }

struct SMem {
  short xhi[16][264], xlo[16][264];
  short hhi[16][264], hlo[16][264];
  float gl[4][16][17];
  float bias[64];
  unsigned rfmin;        // back-pressure min broadcast
};

// Exchange entry = u64 (tag<<32 | bf16hi<<16 | bf16lo), tag = step+1, ring of
// DEPTH slots (slot = s % DEPTH; tag equality disambiguates ring reuse and
// rejects the 0xAA poison). Producers: plain agent-scope atomic store (8B
// atomicity carries tag/data consistency — no fences, no RMW anywhere).
// Cross-layer back-pressure (L0 must not overwrite step s-DEPTH before L1 read
// it) via per-member monotonic rflag words, checked LAZILY against a cached
// min with DEPTH-1 steps of slack — off the critical path in steady state.
template <int LAYER>
__device__ __forceinline__ void lstm_body(
    SMem* sm,
    const float* __restrict__ xin,
    const float* __restrict__ Wih, const float* __restrict__ Whh,
    const float* __restrict__ bih, const float* __restrict__ bhh,
    u64* bx_x, u64* bx_own, unsigned* rflag, float* h1l,
    int g, int mem)
{
  constexpr int KX  = (LAYER == 0) ? 128 : 256;
  constexpr int NKX = KX / 32;
  const int tid = threadIdx.x;
  const int w = tid >> 6, lane = tid & 63, n = lane & 15, q = lane >> 4;
  const int bb = tid >> 4, uu = tid & 15;
  const int B0 = g * 16, U0 = mem * 16;

  // ---- weight slice -> register B-fragments (bf16 hi/lo), once ----
  s8v wxh[NKX], wxl[NKX], whhh[8], whhl[8];
  {
    const int row = w * 256 + U0 + n;
    #pragma unroll
    for (int kf = 0; kf < NKX; ++kf) {
      s8v vh, vl;
      #pragma unroll
      for (int j = 0; j < 8; ++j) { short hi, lo; split_bf16(Wih[row * KX + kf * 32 + q * 8 + j], hi, lo); vh[j] = hi; vl[j] = lo; }
      wxh[kf] = vh; wxl[kf] = vl;
    }
    #pragma unroll
    for (int kf = 0; kf < 8; ++kf) {
      s8v vh, vl;
      #pragma unroll
      for (int j = 0; j < 8; ++j) { short hi, lo; split_bf16(Whh[row * 256 + kf * 32 + q * 8 + j], hi, lo); vh[j] = hi; vl[j] = lo; }
      whhh[kf] = vh; whhl[kf] = vl;
    }
  }
  if (tid < 64) {
    int gate = tid >> 4, u = tid & 15;
    int grow = gate * 256 + U0 + u;
    sm->bias[tid] = bih[grow] + bhh[grow];
  }

  u64* own = bx_own + (size_t)g * DEPTH * 4096;
  u64* src = (LAYER == 1) ? (bx_x + (size_t)g * DEPTH * 4096) : nullptr;
  unsigned* rfg    = rflag + g * 256;           // member m's flag at rfg[m*16]
  unsigned* rfself = rfg + mem * 16;

  float c = 0.f;
  unsigned rf_cached = 0;                       // cached min of partner rflags

  for (int s = 0; s < T_; ++s) {
    // ---- layer0: fp32 x prefetch (in flight during the h-spin) ----
    float xv[8];
    if (LAYER == 0) {
      const float* px = xin + ((size_t)(B0 + bb) * T_ + s) * 128 + uu * 8;
      float4 v0 = *(const float4*)px, v1 = *(const float4*)(px + 4);
      xv[0] = v0.x; xv[1] = v0.y; xv[2] = v0.z; xv[3] = v0.w;
      xv[4] = v1.x; xv[5] = v1.y; xv[6] = v1.z; xv[7] = v1.w;
    }

    // ---- poll phase: ONE combined spin (all loads in flight together) ----
    if (LAYER == 1) {
      const u64* pbx = src + (size_t)(s % DEPTH) * 4096;
      const unsigned xtag = (unsigned)(s + 1);
      u64 xv64[16];
      if (s > 0) {
        const u64* pbh = own + (size_t)((s - 1) % DEPTH) * 4096;
        const unsigned htag = (unsigned)s;
        u64 hv64[16]; int it = 0;
        for (;;) {
          bool ok = true;
          #pragma unroll
          for (int i = 0; i < 16; ++i)
            xv64[i] = __hip_atomic_load(&pbx[i * 256 + tid], __ATOMIC_RELAXED, __HIP_MEMORY_SCOPE_AGENT);
          #pragma unroll
          for (int i = 0; i < 16; ++i)
            hv64[i] = __hip_atomic_load(&pbh[i * 256 + tid], __ATOMIC_RELAXED, __HIP_MEMORY_SCOPE_AGENT);
          #pragma unroll
          for (int i = 0; i < 16; ++i) ok &= ((unsigned)(xv64[i] >> 32) == xtag);
          #pragma unroll
          for (int i = 0; i < 16; ++i) ok &= ((unsigned)(hv64[i] >> 32) == htag);
          if (ok) break;
          if (++it >= 20000) break;          // no-hang safety
          __builtin_amdgcn_s_sleep(1);
        }
        #pragma unroll
        for (int i = 0; i < 16; ++i) {
          unsigned d = (unsigned)hv64[i];
          sm->hhi[i][tid] = (short)(d >> 16);
          sm->hlo[i][tid] = (short)(d & 0xffffu);
        }
      } else {
        int it = 0;
        for (;;) {
          bool ok = true;
          #pragma unroll
          for (int i = 0; i < 16; ++i)
            xv64[i] = __hip_atomic_load(&pbx[i * 256 + tid], __ATOMIC_RELAXED, __HIP_MEMORY_SCOPE_AGENT);
          #pragma unroll
          for (int i = 0; i < 16; ++i) ok &= ((unsigned)(xv64[i] >> 32) == xtag);
          if (ok) break;
          if (++it >= 20000) break;
          __builtin_amdgcn_s_sleep(1);
        }
        #pragma unroll
        for (int i = 0; i < 16; ++i) { sm->hhi[i][tid] = 0; sm->hlo[i][tid] = 0; }
      }
      #pragma unroll
      for (int i = 0; i < 16; ++i) {
        unsigned d = (unsigned)xv64[i];
        sm->xhi[i][tid] = (short)(d >> 16);
        sm->xlo[i][tid] = (short)(d & 0xffffu);
      }
    } else {
      if (s > 0) {
        const u64* pbh = own + (size_t)((s - 1) % DEPTH) * 4096;
        const unsigned htag = (unsigned)s;
        u64 hv64[16]; int it = 0;
        for (;;) {
          bool ok = true;
          #pragma unroll
          for (int i = 0; i < 16; ++i)
            hv64[i] = __hip_atomic_load(&pbh[i * 256 + tid], __ATOMIC_RELAXED, __HIP_MEMORY_SCOPE_AGENT);
          #pragma unroll
          for (int i = 0; i < 16; ++i) ok &= ((unsigned)(hv64[i] >> 32) == htag);
          if (ok) break;
          if (++it >= 20000) break;
          __builtin_amdgcn_s_sleep(1);
        }
        #pragma unroll
        for (int i = 0; i < 16; ++i) {
          unsigned d = (unsigned)hv64[i];
          sm->hhi[i][tid] = (short)(d >> 16);
          sm->hlo[i][tid] = (short)(d & 0xffffu);
        }
      } else {
        #pragma unroll
        for (int i = 0; i < 16; ++i) { sm->hhi[i][tid] = 0; sm->hlo[i][tid] = 0; }
      }
      // stage fp32 x as bf16 hi/lo
      s8v vh, vl;
      #pragma unroll
      for (int j = 0; j < 8; ++j) { short hi, lo; split_bf16(xv[j], hi, lo); vh[j] = hi; vl[j] = lo; }
      *(s8v*)&sm->xhi[bb][uu * 8] = vh;
      *(s8v*)&sm->xlo[bb][uu * 8] = vl;
    }
    __syncthreads();

    // layer1: publish read-progress (all threads' loads done at the barrier)
    if (LAYER == 1 && tid == 0)
      __hip_atomic_store(rfself, (unsigned)(s + 1), __ATOMIC_RELAXED, __HIP_MEMORY_SCOPE_AGENT);

    // ---- bf16x3 MFMA: hi*hi + lo*hi + hi*lo chains ----
    f4v a0 = {0.f, 0.f, 0.f, 0.f}, a1 = a0, a2 = a0;
    #pragma unroll
    for (int kf = 0; kf < NKX; ++kf) {
      s8v ah = *(const s8v*)&sm->xhi[n][kf * 32 + q * 8];
      s8v al = *(const s8v*)&sm->xlo[n][kf * 32 + q * 8];
      a0 = mfma16x16x32(ah, wxh[kf], a0);
      a1 = mfma16x16x32(al, wxh[kf], a1);
      a2 = mfma16x16x32(ah, wxl[kf], a2);
    }
    #pragma unroll
    for (int kf = 0; kf < 8; ++kf) {
      s8v ah = *(const s8v*)&sm->hhi[n][kf * 32 + q * 8];
      s8v al = *(const s8v*)&sm->hlo[n][kf * 32 + q * 8];
      a0 = mfma16x16x32(ah, whhh[kf], a0);
      a1 = mfma16x16x32(al, whhh[kf], a1);
      a2 = mfma16x16x32(ah, whhl[kf], a2);
    }
    f4v D = a0 + (a1 + a2);
    #pragma unroll
    for (int r = 0; r < 4; ++r) sm->gl[w][q * 4 + r][n] = D[r];

    // ---- layer0: lazy back-pressure (wave 0, overlapped with other waves'
    //      MFMA; rare in steady state thanks to DEPTH-1 slack) ----
    bool polled = false;
    if (LAYER == 0 && s >= DEPTH) {
      const unsigned tgt = (unsigned)(s - DEPTH + 1);
      polled = (rf_cached < tgt);
      if (polled && w == 0) {
        unsigned mn; int it = 0;
        for (;;) {
          unsigned v = (lane < 16)
            ? __hip_atomic_load(&rfg[lane * 16], __ATOMIC_RELAXED, __HIP_MEMORY_SCOPE_AGENT)
            : 0xffffffffu;
          mn = v;
          #pragma unroll
          for (int off = 8; off; off >>= 1) {
            unsigned o = __shfl_xor(mn, off, 16);
            mn = (o < mn) ? o : mn;
          }
          if (mn >= tgt) break;
          if (++it >= 20000) break;
          __builtin_amdgcn_s_sleep(1);
        }
        if (lane == 0) sm->rfmin = mn;
      }
    }
    __syncthreads();
    if (polled) rf_cached = sm->rfmin;   // deterministic: same decision on all threads

    // ---- activations + state ----
    float pi = sm->gl[0][bb][uu] + sm->bias[uu];
    float pf = sm->gl[1][bb][uu] + sm->bias[16 + uu];
    float pg = sm->gl[2][bb][uu] + sm->bias[32 + uu];
    float po = sm->gl[3][bb][uu] + sm->bias[48 + uu];
    float ig = sig_(pi), fg = sig_(pf), gg = th_(pg), og = sig_(po);
    c = fg * c + ig * gg;
    float h = og * th_(c);

    // ---- publish h (tagged, fire-and-forget) ----
    u64 val = ((u64)(unsigned)(s + 1) << 32) | (u64)pack_hilo(h);
    __hip_atomic_store(&own[(size_t)(s % DEPTH) * 4096 + bb * 256 + U0 + uu], val,
                       __ATOMIC_RELAXED, __HIP_MEMORY_SCOPE_AGENT);

    if (LAYER == 1 && s == T_ - 1)
      h1l[(B0 + bb) * H_ + U0 + uu] = h;
  }
}

__global__ __launch_bounds__(256, 2) void lstm_fused(
    const float* __restrict__ x,
    const float* __restrict__ Wih0, const float* __restrict__ Whh0,
    const float* __restrict__ bih0, const float* __restrict__ bhh0,
    const float* __restrict__ Wih1, const float* __restrict__ Whh1,
    const float* __restrict__ bih1, const float* __restrict__ bhh1,
    u64* bx0, u64* bx1, unsigned* rflag, float* h1l)
{
  __shared__ SMem sm;
  const int bid = blockIdx.x;
  if (bid < 256) {
    lstm_body<0>(&sm, x, Wih0, Whh0, bih0, bhh0, nullptr, bx0, rflag, nullptr,
                 bid >> 4, bid & 15);
  } else {
    const int b = bid - 256;
    lstm_body<1>(&sm, nullptr, Wih1, Whh1, bih1, bhh1, bx0, bx1, rflag, h1l,
                 b >> 4, b & 15);
  }
}

__global__ void fc_kernel(const float* __restrict__ h1l, const float* __restrict__ Wfc,
                          float* __restrict__ out) {
  __shared__ float hs[H_];
  const int b = blockIdx.x, o = threadIdx.x;
  hs[o]       = h1l[b * H_ + o];
  hs[o + 128] = h1l[b * H_ + o + 128];
  __syncthreads();
  float acc = 0.f;
  #pragma unroll 8
  for (int u = 0; u < H_; u += 4) {
    float4 wv = *(const float4*)&Wfc[o * H_ + u];
    acc += wv.x * hs[u] + wv.y * hs[u + 1] + wv.z * hs[u + 2] + wv.w * hs[u + 3];
  }
  out[b * OUTD + o] = acc;
}

extern "C" void kernel_launch(void* const* d_in, const int* in_sizes, int n_in,
                              void* d_out, int out_size, void* d_ws, size_t ws_size,
                              hipStream_t stream) {
  const float* x    = (const float*)d_in[0];
  const float* Wih0 = (const float*)d_in[1];
  const float* Whh0 = (const float*)d_in[2];
  const float* bih0 = (const float*)d_in[3];
  const float* bhh0 = (const float*)d_in[4];
  const float* Wih1 = (const float*)d_in[5];
  const float* Whh1 = (const float*)d_in[6];
  const float* bih1 = (const float*)d_in[7];
  const float* bhh1 = (const float*)d_in[8];
  const float* Wfc  = (const float*)d_in[9];

  // ws: bx0 (4 MiB) | bx1 (4 MiB) | rflag (16 KiB) | h1l (256 KiB)
  u64*      bx0   = (u64*)d_ws;                     // 16*DEPTH*4096
  u64*      bx1   = bx0 + 16 * DEPTH * 4096;        // 16*DEPTH*4096
  unsigned* rflag = (unsigned*)(bx1 + 16 * DEPTH * 4096);  // 16*16*16
  float*    h1l   = (float*)(rflag + 4096);                // 256*256

  // rflag must start 0 (poison 0xAA.. would spoof the >= check; exchange tags
  // use equality so poison can never match them).
  hipMemsetAsync(rflag, 0, 4096 * sizeof(unsigned), stream);

  lstm_fused<<<512, 256, 0, stream>>>(x, Wih0, Whh0, bih0, bhh0,
                                      Wih1, Whh1, bih1, bhh1,
                                      bx0, bx1, rflag, h1l);
  fc_kernel<<<256, 128, 0, stream>>>(h1l, Wfc, (float*)d_out);
}

// Round 4
// 3113.957 us; speedup vs baseline: 1.3265x; 1.3265x over previous
//
#include <hip/hip_runtime.h>
#include <stdint.h>

#define T_    512
#define H_    256
#define OUTD  128
#define DEPTH 4          // exchange ring depth; slack 3 decouples back-pressure

typedef unsigned long long u64;
typedef __attribute__((ext_vector_type(8))) short s8v;
typedef __attribute__((ext_vector_type(4))) float f4v;

__device__ __forceinline__ f4v mfma16x16x32(s8v a, s8v b, f4v c) {
  return __builtin_amdgcn_mfma_f32_16x16x32_bf16(a, b, c, 0, 0, 0);
}

// fp32 -> bf16 hi (truncate) + bf16 lo (RN of remainder)
__device__ __forceinline__ void split_bf16(float f, short &hi, short &lo) {
  unsigned u  = __float_as_uint(f);
  unsigned uh = u & 0xffff0000u;
  hi = (short)(uh >> 16);
  float r = f - __uint_as_float(uh);
  unsigned ur = __float_as_uint(r);
  lo = (short)((ur + 0x7fffu + ((ur >> 16) & 1u)) >> 16);
}

__device__ __forceinline__ unsigned pack_hilo(float f) {
  short hi, lo; split_bf16(f, hi, lo);
  return ((unsigned)(unsigned short)hi << 16) | (unsigned)(unsigned short)lo;
}

__device__ __forceinline__ float sig_(float x) { return 1.f / (1.f + __expf(-x)); }
__device__ __forceinline__ float th_(float x)  { float e = __expf(2.f * x); return 1.f - 2.f / (e + 1.f); }

struct SMem {
  short xhi[16][264], xlo[16][264];
  short hhi[16][264], hlo[16][264];
  float gl[4][16][17];
  float bias[64];
  unsigned rfmin;        // back-pressure min broadcast
};

// Exchange entry = u64 (tag<<32 | bf16hi<<16 | bf16lo), tag = step+1, ring of
// DEPTH slots (slot = s % DEPTH; tag equality disambiguates reuse and rejects
// 0xAA poison). Producers: plain agent-scope atomic store (8B atomicity
// carries tag/data consistency — no fences, no RMW anywhere). Own-group ring
// reuse is safe by induction (observing h_{s-1} from all members implies all
// consumed h_{s-2}, ... so slot age DEPTH>=2 is never live). Cross-layer reuse
// (L0 overwriting x that L1 hasn't read) is guarded by per-member monotonic
// rflag words, checked LAZILY against a cached min with DEPTH-1 slack.
template <int LAYER>
__device__ __forceinline__ void lstm_body(
    SMem* sm,
    const float* __restrict__ xin,
    const float* __restrict__ Wih, const float* __restrict__ Whh,
    const float* __restrict__ bih, const float* __restrict__ bhh,
    u64* bx_x, u64* bx_own, unsigned* rflag, float* h1l,
    int g, int mem)
{
  constexpr int KX  = (LAYER == 0) ? 128 : 256;
  constexpr int NKX = KX / 32;
  const int tid = threadIdx.x;
  const int w = tid >> 6, lane = tid & 63, n = lane & 15, q = lane >> 4;
  const int bb = tid >> 4, uu = tid & 15;
  const int B0 = g * 16, U0 = mem * 16;

  // ---- weight slice -> register B-fragments (bf16 hi/lo), once ----
  s8v wxh[NKX], wxl[NKX], whhh[8], whhl[8];
  {
    const int row = w * 256 + U0 + n;
    #pragma unroll
    for (int kf = 0; kf < NKX; ++kf) {
      s8v vh, vl;
      #pragma unroll
      for (int j = 0; j < 8; ++j) { short hi, lo; split_bf16(Wih[row * KX + kf * 32 + q * 8 + j], hi, lo); vh[j] = hi; vl[j] = lo; }
      wxh[kf] = vh; wxl[kf] = vl;
    }
    #pragma unroll
    for (int kf = 0; kf < 8; ++kf) {
      s8v vh, vl;
      #pragma unroll
      for (int j = 0; j < 8; ++j) { short hi, lo; split_bf16(Whh[row * 256 + kf * 32 + q * 8 + j], hi, lo); vh[j] = hi; vl[j] = lo; }
      whhh[kf] = vh; whhl[kf] = vl;
    }
  }
  if (tid < 64) {
    int gate = tid >> 4, u = tid & 15;
    int grow = gate * 256 + U0 + u;
    sm->bias[tid] = bih[grow] + bhh[grow];
  }

  u64* own = bx_own + (size_t)g * DEPTH * 4096;
  u64* src = (LAYER == 1) ? (bx_x + (size_t)g * DEPTH * 4096) : nullptr;
  unsigned* rfg    = rflag + g * 256;           // member m's flag at rfg[m*16]
  unsigned* rfself = rfg + mem * 16;

  float c = 0.f;
  unsigned rf_cached = 0;

  for (int s = 0; s < T_; ++s) {
    // ---- layer0: fp32 x prefetch (in flight during the h-spin) ----
    float xv[8];
    u64 xv64[16];
    if (LAYER == 0) {
      const float* px = xin + ((size_t)(B0 + bb) * T_ + s) * 128 + uu * 8;
      float4 v0 = *(const float4*)px, v1 = *(const float4*)(px + 4);
      xv[0] = v0.x; xv[1] = v0.y; xv[2] = v0.z; xv[3] = v0.w;
      xv[4] = v1.x; xv[5] = v1.y; xv[6] = v1.z; xv[7] = v1.w;
    } else {
      // issue ONE round of x loads now; latency overlaps the h spin below
      const u64* pbx = src + (size_t)(s % DEPTH) * 4096;
      #pragma unroll
      for (int i = 0; i < 16; ++i)
        xv64[i] = __hip_atomic_load(&pbx[i * 256 + tid], __ATOMIC_RELAXED, __HIP_MEMORY_SCOPE_AGENT);
    }

    // ---- h-only spin (16 loads per retry) ----
    if (s > 0) {
      const u64* pbh = own + (size_t)((s - 1) % DEPTH) * 4096;
      const unsigned htag = (unsigned)s;
      u64 hv64[16]; int it = 0;
      for (;;) {
        bool ok = true;
        #pragma unroll
        for (int i = 0; i < 16; ++i)
          hv64[i] = __hip_atomic_load(&pbh[i * 256 + tid], __ATOMIC_RELAXED, __HIP_MEMORY_SCOPE_AGENT);
        #pragma unroll
        for (int i = 0; i < 16; ++i) ok &= ((unsigned)(hv64[i] >> 32) == htag);
        if (ok) break;
        if (++it >= 20000) break;          // no-hang safety
        __builtin_amdgcn_s_sleep(1);
      }
      #pragma unroll
      for (int i = 0; i < 16; ++i) {
        unsigned d = (unsigned)hv64[i];
        sm->hhi[i][tid] = (short)(d >> 16);
        sm->hlo[i][tid] = (short)(d & 0xffffu);
      }
    } else {
      #pragma unroll
      for (int i = 0; i < 16; ++i) { sm->hhi[i][tid] = 0; sm->hlo[i][tid] = 0; }
    }

    // ---- x: verify tags (first round usually suffices); stage to LDS ----
    if (LAYER == 1) {
      const u64* pbx = src + (size_t)(s % DEPTH) * 4096;
      const unsigned xtag = (unsigned)(s + 1);
      bool ok = true;
      #pragma unroll
      for (int i = 0; i < 16; ++i) ok &= ((unsigned)(xv64[i] >> 32) == xtag);
      int it = 0;
      while (!ok) {
        ok = true;
        #pragma unroll
        for (int i = 0; i < 16; ++i)
          xv64[i] = __hip_atomic_load(&pbx[i * 256 + tid], __ATOMIC_RELAXED, __HIP_MEMORY_SCOPE_AGENT);
        #pragma unroll
        for (int i = 0; i < 16; ++i) ok &= ((unsigned)(xv64[i] >> 32) == xtag);
        if (ok) break;
        if (++it >= 20000) break;
        __builtin_amdgcn_s_sleep(1);
      }
      #pragma unroll
      for (int i = 0; i < 16; ++i) {
        unsigned d = (unsigned)xv64[i];
        sm->xhi[i][tid] = (short)(d >> 16);
        sm->xlo[i][tid] = (short)(d & 0xffffu);
      }
    } else {
      s8v vh, vl;
      #pragma unroll
      for (int j = 0; j < 8; ++j) { short hi, lo; split_bf16(xv[j], hi, lo); vh[j] = hi; vl[j] = lo; }
      *(s8v*)&sm->xhi[bb][uu * 8] = vh;
      *(s8v*)&sm->xlo[bb][uu * 8] = vl;
    }
    __syncthreads();

    // layer1: publish read-progress (all threads' loads done at the barrier)
    if (LAYER == 1 && tid == 0)
      __hip_atomic_store(rfself, (unsigned)(s + 1), __ATOMIC_RELAXED, __HIP_MEMORY_SCOPE_AGENT);

    // ---- bf16x3 MFMA: hi*hi + lo*hi + hi*lo chains ----
    f4v a0 = {0.f, 0.f, 0.f, 0.f}, a1 = a0, a2 = a0;
    #pragma unroll
    for (int kf = 0; kf < NKX; ++kf) {
      s8v ah = *(const s8v*)&sm->xhi[n][kf * 32 + q * 8];
      s8v al = *(const s8v*)&sm->xlo[n][kf * 32 + q * 8];
      a0 = mfma16x16x32(ah, wxh[kf], a0);
      a1 = mfma16x16x32(al, wxh[kf], a1);
      a2 = mfma16x16x32(ah, wxl[kf], a2);
    }
    #pragma unroll
    for (int kf = 0; kf < 8; ++kf) {
      s8v ah = *(const s8v*)&sm->hhi[n][kf * 32 + q * 8];
      s8v al = *(const s8v*)&sm->hlo[n][kf * 32 + q * 8];
      a0 = mfma16x16x32(ah, whhh[kf], a0);
      a1 = mfma16x16x32(al, whhh[kf], a1);
      a2 = mfma16x16x32(ah, whhl[kf], a2);
    }
    f4v D = a0 + (a1 + a2);
    #pragma unroll
    for (int r = 0; r < 4; ++r) sm->gl[w][q * 4 + r][n] = D[r];

    // ---- layer0: lazy back-pressure for THIS step's publish slot (s%DEPTH
    //      holds step s-DEPTH; L1 must have read it). Wave 0 polls while
    //      waves 1-3 sit at the barrier; slack DEPTH-1 keeps it non-blocking
    //      in steady state. ----
    bool polled = false;
    if (LAYER == 0 && s >= DEPTH) {
      const unsigned tgt = (unsigned)(s - DEPTH + 1);
      polled = (rf_cached < tgt);
      if (polled && w == 0) {
        unsigned mn; int it = 0;
        for (;;) {
          unsigned v = (lane < 16)
            ? __hip_atomic_load(&rfg[lane * 16], __ATOMIC_RELAXED, __HIP_MEMORY_SCOPE_AGENT)
            : 0xffffffffu;
          mn = v;
          #pragma unroll
          for (int off = 8; off; off >>= 1) {
            unsigned o = __shfl_xor(mn, off, 16);
            mn = (o < mn) ? o : mn;
          }
          if (mn >= tgt) break;
          if (++it >= 20000) break;
          __builtin_amdgcn_s_sleep(1);
        }
        if (lane == 0) sm->rfmin = mn;
      }
    }
    __syncthreads();
    if (polled) rf_cached = sm->rfmin;   // uniform decision on all threads

    // ---- activations + state ----
    float pi = sm->gl[0][bb][uu] + sm->bias[uu];
    float pf = sm->gl[1][bb][uu] + sm->bias[16 + uu];
    float pg = sm->gl[2][bb][uu] + sm->bias[32 + uu];
    float po = sm->gl[3][bb][uu] + sm->bias[48 + uu];
    float ig = sig_(pi), fg = sig_(pf), gg = th_(pg), og = sig_(po);
    c = fg * c + ig * gg;
    float h = og * th_(c);

    // ---- publish h first (critical path), then side outputs ----
    u64 val = ((u64)(unsigned)(s + 1) << 32) | (u64)pack_hilo(h);
    __hip_atomic_store(&own[(size_t)(s % DEPTH) * 4096 + bb * 256 + U0 + uu], val,
                       __ATOMIC_RELAXED, __HIP_MEMORY_SCOPE_AGENT);

    if (LAYER == 1 && s == T_ - 1)
      h1l[(B0 + bb) * H_ + U0 + uu] = h;
  }
}

__global__ __launch_bounds__(256, 2) void lstm_fused(
    const float* __restrict__ x,
    const float* __restrict__ Wih0, const float* __restrict__ Whh0,
    const float* __restrict__ bih0, const float* __restrict__ bhh0,
    const float* __restrict__ Wih1, const float* __restrict__ Whh1,
    const float* __restrict__ bih1, const float* __restrict__ bhh1,
    u64* bx0, u64* bx1, unsigned* rflag, float* h1l)
{
  __shared__ SMem sm;
  const int bid = blockIdx.x;
  if (bid < 256) {
    lstm_body<0>(&sm, x, Wih0, Whh0, bih0, bhh0, nullptr, bx0, rflag, nullptr,
                 bid >> 4, bid & 15);
  } else {
    const int b = bid - 256;
    lstm_body<1>(&sm, nullptr, Wih1, Whh1, bih1, bhh1, bx0, bx1, rflag, h1l,
                 b >> 4, b & 15);
  }
}

__global__ void fc_kernel(const float* __restrict__ h1l, const float* __restrict__ Wfc,
                          float* __restrict__ out) {
  __shared__ float hs[H_];
  const int b = blockIdx.x, o = threadIdx.x;
  hs[o]       = h1l[b * H_ + o];
  hs[o + 128] = h1l[b * H_ + o + 128];
  __syncthreads();
  float acc = 0.f;
  #pragma unroll 8
  for (int u = 0; u < H_; u += 4) {
    float4 wv = *(const float4*)&Wfc[o * H_ + u];
    acc += wv.x * hs[u] + wv.y * hs[u + 1] + wv.z * hs[u + 2] + wv.w * hs[u + 3];
  }
  out[b * OUTD + o] = acc;
}

extern "C" void kernel_launch(void* const* d_in, const int* in_sizes, int n_in,
                              void* d_out, int out_size, void* d_ws, size_t ws_size,
                              hipStream_t stream) {
  const float* x    = (const float*)d_in[0];
  const float* Wih0 = (const float*)d_in[1];
  const float* Whh0 = (const float*)d_in[2];
  const float* bih0 = (const float*)d_in[3];
  const float* bhh0 = (const float*)d_in[4];
  const float* Wih1 = (const float*)d_in[5];
  const float* Whh1 = (const float*)d_in[6];
  const float* bih1 = (const float*)d_in[7];
  const float* bhh1 = (const float*)d_in[8];
  const float* Wfc  = (const float*)d_in[9];

  // ws: bx0 (2 MiB) | bx1 (2 MiB) | rflag (16 KiB) | h1l (256 KiB)
  u64*      bx0   = (u64*)d_ws;                            // 16*DEPTH*4096
  u64*      bx1   = bx0 + 16 * DEPTH * 4096;               // 16*DEPTH*4096
  unsigned* rflag = (unsigned*)(bx1 + 16 * DEPTH * 4096);  // 16*16*16
  float*    h1l   = (float*)(rflag + 4096);                // 256*256

  // rflag must start 0 (poison 0xAA.. would spoof the >= check; exchange tags
  // use equality so poison can never match them).
  hipMemsetAsync(rflag, 0, 4096 * sizeof(unsigned), stream);

  lstm_fused<<<512, 256, 0, stream>>>(x, Wih0, Whh0, bih0, bhh0,
                                      Wih1, Whh1, bih1, bhh1,
                                      bx0, bx1, rflag, h1l);
  fc_kernel<<<256, 128, 0, stream>>>(h1l, Wfc, (float*)d_out);
}